// Round 13
// baseline (381.235 us; speedup 1.0000x reference)
//
#include <hip/hip_runtime.h>
#include <hip/hip_fp16.h>

#define S_TOK 8192
#define DDIM  1024
#define HDIM  4096
#define NEXP  8
#define CAP   1024

typedef __attribute__((ext_vector_type(8))) _Float16 half8;
typedef __attribute__((ext_vector_type(16))) float f32x16;

__device__ __forceinline__ void load_lds16(const _Float16* g, _Float16* l) {
  __builtin_amdgcn_global_load_lds(
      (const __attribute__((address_space(1))) unsigned int*)g,
      (__attribute__((address_space(3))) unsigned int*)l, 16, 0, 0);
}

// ---------------- gating: logits = x @ wg, softmax, top-1 ----------------
__global__ __launch_bounds__(256) void moe_gating(const float* __restrict__ x,
                                                  const float* __restrict__ wg,
                                                  int* __restrict__ eidx,
                                                  float* __restrict__ gtok) {
  const int s = blockIdx.x * 4 + (threadIdx.x >> 6);
  const int lane = threadIdx.x & 63;
  const float* xr = x + (size_t)s * DDIM;
  float acc[NEXP];
#pragma unroll
  for (int e = 0; e < NEXP; ++e) acc[e] = 0.f;
  for (int d = lane; d < DDIM; d += 64) {
    float xv = xr[d];
    const float4* wrow = (const float4*)(wg + (size_t)d * NEXP);
    float4 w0 = wrow[0], w1v = wrow[1];
    acc[0] += xv * w0.x;  acc[1] += xv * w0.y;
    acc[2] += xv * w0.z;  acc[3] += xv * w0.w;
    acc[4] += xv * w1v.x; acc[5] += xv * w1v.y;
    acc[6] += xv * w1v.z; acc[7] += xv * w1v.w;
  }
#pragma unroll
  for (int off = 32; off > 0; off >>= 1) {
#pragma unroll
    for (int e = 0; e < NEXP; ++e) acc[e] += __shfl_down(acc[e], off);
  }
  if (lane == 0) {
    int best = 0; float bv = acc[0];
#pragma unroll
    for (int e = 1; e < NEXP; ++e) if (acc[e] > bv) { bv = acc[e]; best = e; }
    float sum = 0.f;
#pragma unroll
    for (int e = 0; e < NEXP; ++e) sum += expf(acc[e] - bv);
    eidx[s] = best;
    gtok[s] = 1.f / sum;   // exp(best - max) == 1
  }
}

// ---------------- hierarchical ordered slot assignment ----------------
__global__ __launch_bounds__(64) void scanA(const int* __restrict__ eidx,
                                            int* __restrict__ cnt) {
  const int blk = blockIdx.x;        // 128 blocks x 64 tokens
  const int lane = threadIdx.x;
  int e = eidx[blk * 64 + lane];
#pragma unroll
  for (int w = 0; w < NEXP; ++w) {
    unsigned long long m = __ballot(e == w);
    if (lane == 0) cnt[blk * NEXP + w] = __popcll(m);
  }
}

__global__ __launch_bounds__(512) void scanB(const int* __restrict__ cnt,
                                             int* __restrict__ off) {
  const int w = threadIdx.x >> 6;
  const int l = threadIdx.x & 63;
  int c0 = cnt[(2 * l) * NEXP + w];
  int c1 = cnt[(2 * l + 1) * NEXP + w];
  int s = c0 + c1;
  int run = s;
#pragma unroll
  for (int d = 1; d < 64; d <<= 1) {
    int up = __shfl_up(run, d);
    if (l >= d) run += up;
  }
  int excl = run - s;
  off[(2 * l) * NEXP + w] = excl;
  off[(2 * l + 1) * NEXP + w] = excl + c0;
}

__global__ __launch_bounds__(64) void scanC(const int* __restrict__ eidx,
                                            const float* __restrict__ gtok,
                                            const int* __restrict__ off,
                                            int* __restrict__ s2t,
                                            float* __restrict__ rgate) {
  const int blk = blockIdx.x;
  const int lane = threadIdx.x;
  const int tok = blk * 64 + lane;
  int e = eidx[tok];
  float g = gtok[tok];
  const unsigned long long below = (1ull << lane) - 1ull;
#pragma unroll
  for (int w = 0; w < NEXP; ++w) {
    unsigned long long m = __ballot(e == w);
    if (e == w) {
      int slot = off[blk * NEXP + w] + __popcll(m & below);
      if (slot < CAP) { s2t[w * CAP + slot] = tok; rgate[w * CAP + slot] = g; }
    }
  }
}

// ---------------- dispatch: gather kept tokens, fp32 -> fp16 ----------------
__global__ __launch_bounds__(128) void moe_dispatch(const float* __restrict__ x,
                                                    const int* __restrict__ s2t,
                                                    _Float16* __restrict__ disp) {
  const int row = blockIdx.x;
  const int t = threadIdx.x;
  const int token = s2t[row];
  half8 v;
  if (token >= 0) {
    const float4* xr = (const float4*)(x + (size_t)token * DDIM);
    float4 a = xr[2 * t], b = xr[2 * t + 1];
    v[0] = (_Float16)a.x; v[1] = (_Float16)a.y; v[2] = (_Float16)a.z; v[3] = (_Float16)a.w;
    v[4] = (_Float16)b.x; v[5] = (_Float16)b.y; v[6] = (_Float16)b.z; v[7] = (_Float16)b.w;
  } else {
#pragma unroll
    for (int i = 0; i < 8; ++i) v[i] = (_Float16)0.f;
  }
  *(half8*)(disp + (size_t)row * DDIM + t * 8) = v;
}

// ---------------- grouped GEMM "fused-B v2": 2-iteration-deep B pipeline ----------------
// C = A[z] @ B[z], A fp16 [M][K] (gload_lds + XOR swizzle), B fp32 [K][N] native ->
// reg-stage (2 named sets, 2 tiles ahead), cvt fp16, ds_write into [n][64k] XOR tile.
// BM=BN=128, BK=64. 256 thr = 4 waves (2Mx2N), wave tile 64x64. LDS 64 KB, 2 blk/CU.
// Counted-vmcnt barrier: s_waitcnt vmcnt(8) lgkmcnt(0); s_barrier — every barrier
// leaves exactly the NEXT write-set's 8 B-loads in flight; A's 4 gload_lds are the
// oldest 4 of 12 outstanding -> drained. B-load latency window = 2 iters (~5000 cy).
// Unroll-by-2 so reg-set & buffer indices are compile-time (rule #20).
// B swizzle f(n)=((n>>2)^n)&7 (write & read conflict-free, enumerated r12).
// Tile order m-fastest (L2: live B/XCD = 4 MB). rot=(widx&7)*(NT/8) decorrelates
// co-resident (adjacent-widx) blocks' addresses.
template <int KDIM, int NDIM, bool FIRST, int GX, int GY>
__global__ __launch_bounds__(256, 2) void ffn_gemm_f(const _Float16* __restrict__ A_set,
                                                     const float* __restrict__ B_set,
                                                     _Float16* __restrict__ Hout,
                                                     float* __restrict__ Y,
                                                     const int* __restrict__ s2t,
                                                     const float* __restrict__ rgate) {
  __shared__ __align__(16) _Float16 As[2 * 8192];   // [buf][128 rows][64 k]
  __shared__ __align__(16) _Float16 Bs[2 * 8192];   // [buf][128 n][64 k] (XOR chunks)
  constexpr int NT = KDIM / 64;
  constexpr int TILES = GX * GY;
  const int wg = blockIdx.x;
  const int swz = (wg & 7) * TILES + (wg >> 3);   // bijective; xcd == expert
  const int z = swz / TILES;
  const int s2 = swz % TILES;
  const int xx = s2 / GY;          // n-tile (slow)
  const int yy = s2 % GY;          // m-tile (fast) -> concurrent blocks share B
  const int m0 = yy * 128, n0 = xx * 128;
  const int widx = wg >> 3;
  const int rot = (widx & 7) * (NT / 8);   // adjacent blocks -> different K phase

  const int tid = threadIdx.x;
  const _Float16* Ae = A_set + (size_t)z * 1024 * KDIM;
  const float* Be = B_set + (size_t)z * (size_t)KDIM * NDIM;

  // A staging (global_load_lds, source-XOR-swizzled, linear LDS dest)
  const int sr = tid >> 3;      // row within 32-row group
  const int sc = tid & 7;       // 16B chunk
  auto STAGE_A = [&](int buf, int kt) {
#pragma unroll
    for (int j = 0; j < 4; ++j) {
      int r = j * 32 + sr;
      load_lds16(Ae + (size_t)(m0 + r) * KDIM + kt * 64 + ((sc ^ (r & 7)) << 3),
                 As + buf * 8192 + j * 2048 + tid * 8);
    }
  };

  // B reg-staging: thread t -> n-quad q = t&31 (n = 4q..4q+3), k-rows kb..kb+7
  const int bq = tid & 31;
  const int bkb = (tid >> 5) * 8;
  auto LOAD_B = [&](float4* br, int kt) {
#pragma unroll
    for (int i = 0; i < 8; ++i)
      br[i] = *(const float4*)(Be + (size_t)(kt * 64 + bkb + i) * NDIM + n0 + 4 * bq);
  };
  auto WRITE_B = [&](const float4* br, int buf) {
    _Float16* Bb = Bs + buf * 8192;
#pragma unroll
    for (int w = 0; w < 4; ++w) {
      int n = 4 * bq + w;
      half8 h;
#pragma unroll
      for (int i = 0; i < 8; ++i) h[i] = (_Float16)br[i][w];
      int c = (bkb >> 3) ^ (((n >> 2) ^ n) & 7);
      *(half8*)(Bb + n * 64 + c * 8) = h;
    }
  };

  const int lane = tid & 63, wid = tid >> 6;
  const int wr = (wid >> 1) * 64;   // wave A-row base
  const int wc = (wid & 1) * 64;    // wave B-n base
  const int r32 = lane & 31;
  const int khalf = lane >> 5;
  int offA[2][4], offB[2][4];
#pragma unroll
  for (int t2 = 0; t2 < 2; ++t2)
#pragma unroll
    for (int kf = 0; kf < 4; ++kf) {
      int ra = wr + t2 * 32 + r32, c = kf * 2 + khalf;
      offA[t2][kf] = ra * 64 + ((c ^ (ra & 7)) << 3);
      int nb = wc + t2 * 32 + r32;
      offB[t2][kf] = nb * 64 + ((c ^ (((nb >> 2) ^ nb) & 7)) << 3);
    }

  f32x16 acc[2][2];
#pragma unroll
  for (int m = 0; m < 2; ++m)
#pragma unroll
    for (int n = 0; n < 2; ++n)
#pragma unroll
      for (int j = 0; j < 16; ++j) acc[m][n][j] = 0.f;

  auto COMPUTE = [&](int buf) {
    const _Float16* Ab = As + buf * 8192;
    const _Float16* Bb = Bs + buf * 8192;
    __builtin_amdgcn_s_setprio(1);
#pragma unroll
    for (int kf = 0; kf < 4; ++kf) {
      half8 a0 = *(const half8*)(Ab + offA[0][kf]);
      half8 a1 = *(const half8*)(Ab + offA[1][kf]);
      half8 b0 = *(const half8*)(Bb + offB[0][kf]);
      half8 b1 = *(const half8*)(Bb + offB[1][kf]);
      acc[0][0] = __builtin_amdgcn_mfma_f32_32x32x16_f16(a0, b0, acc[0][0], 0, 0, 0);
      acc[0][1] = __builtin_amdgcn_mfma_f32_32x32x16_f16(a0, b1, acc[0][1], 0, 0, 0);
      acc[1][0] = __builtin_amdgcn_mfma_f32_32x32x16_f16(a1, b0, acc[1][0], 0, 0, 0);
      acc[1][1] = __builtin_amdgcn_mfma_f32_32x32x16_f16(a1, b1, acc[1][1], 0, 0, 0);
    }
    __builtin_amdgcn_s_setprio(0);
  };

  // Counted-vmcnt barrier: keep the newest 8 VMEM (next B set) in flight.
#define BARRIER8 do { \
    asm volatile("s_waitcnt vmcnt(8) lgkmcnt(0)" ::: "memory"); \
    __builtin_amdgcn_sched_barrier(0); \
    __builtin_amdgcn_s_barrier(); \
    __builtin_amdgcn_sched_barrier(0); } while (0)

  float4 bregA[8], bregB[8];
  // prologue: tile t0 fully staged; t1's B-loads in flight across the barrier
  LOAD_B(bregA, rot);
  STAGE_A(0, rot);
  WRITE_B(bregA, 0);                       // waits bregA only (A4 newer)
  LOAD_B(bregB, (rot + 1) & (NT - 1));
  BARRIER8;                                // drains A4; bregB stays flying

#pragma unroll 1
  for (int i = 0; i < NT; i += 2) {
    // ---- even iter j=i: compute buf0(tile i); publish buf1(tile i+1) ----
    STAGE_A(1, (i + 1 + rot) & (NT - 1));
    LOAD_B(bregA, (i + 2 + rot) & (NT - 1));   // 2 tiles ahead (junk at tail, unused)
    COMPUTE(0);
    WRITE_B(bregB, 1);                          // vmcnt(12): keeps A4+bregA8 flying
    BARRIER8;
    // ---- odd iter j=i+1: compute buf1(tile i+1); publish buf0(tile i+2) ----
    if (i + 2 < NT) STAGE_A(0, (i + 2 + rot) & (NT - 1));
    LOAD_B(bregB, (i + 3 + rot) & (NT - 1));
    COMPUTE(1);
    if (i + 2 < NT) WRITE_B(bregA, 0);
    BARRIER8;
  }
#undef BARRIER8

  // epilogue: C/D layout col=lane&31, row=(reg&3)+8*(reg>>2)+4*(lane>>5)
#pragma unroll
  for (int mt = 0; mt < 2; ++mt) {
#pragma unroll
    for (int nt = 0; nt < 2; ++nt) {
      const int gcol = n0 + wc + nt * 32 + r32;
#pragma unroll
      for (int reg = 0; reg < 16; ++reg) {
        const int rowf = (reg & 3) + 8 * (reg >> 2) + 4 * khalf;
        const int grow = m0 + wr + mt * 32 + rowf;
        if (FIRST) {
          Hout[((size_t)z * 1024 + grow) * (size_t)NDIM + gcol] =
              (_Float16)fmaxf(acc[mt][nt][reg], 0.f);
        } else {
          int token = s2t[z * CAP + grow];
          if (token >= 0) {
            float g = rgate[z * CAP + grow];
            Y[(size_t)token * DDIM + gcol] = acc[mt][nt][reg] * g;
          }
        }
      }
    }
  }
}

extern "C" void kernel_launch(void* const* d_in, const int* in_sizes, int n_in,
                              void* d_out, int out_size, void* d_ws, size_t ws_size,
                              hipStream_t stream) {
  const float* x  = (const float*)d_in[0];
  const float* wg = (const float*)d_in[1];
  const float* w1 = (const float*)d_in[2];
  const float* w2 = (const float*)d_in[3];
  float* y = (float*)d_out;

  char* ws = (char*)d_ws;
  int*   eidx  = (int*)(ws);                 // 32 KB
  float* gtok  = (float*)(ws + 32768);       // 32 KB
  int*   s2t   = (int*)(ws + 65536);         // 32 KB
  float* rgate = (float*)(ws + 98304);       // 32 KB
  int*   cnt   = (int*)(ws + 131072);        // 4 KB
  int*   off   = (int*)(ws + 135168);        // 4 KB
  _Float16* disp = (_Float16*)(ws + 147456); // 16 MB
  _Float16* hbuf = (_Float16*)(ws + 147456 + (size_t)NEXP * CAP * DDIM * 2);  // 64 MB

  moe_gating<<<S_TOK / 4, 256, 0, stream>>>(x, wg, eidx, gtok);
  scanA<<<128, 64, 0, stream>>>(eidx, cnt);
  scanB<<<1, 512, 0, stream>>>(cnt, off);
  (void)hipMemsetAsync(s2t, 0xFF, 32768, stream);
  (void)hipMemsetAsync(rgate, 0, 32768, stream);
  scanC<<<128, 64, 0, stream>>>(eidx, gtok, off, s2t, rgate);
  moe_dispatch<<<NEXP * CAP, 128, 0, stream>>>(x, s2t, disp);
  (void)hipMemsetAsync(d_out, 0, (size_t)out_size * sizeof(float), stream);

  // GEMM1: disp[C,1024] x w1[1024,4096] -> relu -> hbuf. 8e x (32n x 8m) = 2048 blocks
  ffn_gemm_f<DDIM, HDIM, true, 32, 8><<<2048, 256, 0, stream>>>(
      disp, w1, hbuf, nullptr, nullptr, nullptr);

  // GEMM2: hbuf[C,4096] x w2[4096,1024] -> scatter to y. 8e x (8n x 8m) = 512 blocks
  ffn_gemm_f<HDIM, DDIM, false, 8, 8><<<512, 256, 0, stream>>>(
      hbuf, w2, nullptr, y, s2t, rgate);
}

// Round 14
// 292.945 us; speedup vs baseline: 1.3014x; 1.3014x over previous
//
#include <hip/hip_runtime.h>
#include <hip/hip_fp16.h>

#define S_TOK 8192
#define DDIM  1024
#define HDIM  4096
#define NEXP  8
#define CAP   1024

typedef __attribute__((ext_vector_type(8))) _Float16 half8;
typedef __attribute__((ext_vector_type(16))) float f32x16;

__device__ __forceinline__ void load_lds16(const _Float16* g, _Float16* l) {
  __builtin_amdgcn_global_load_lds(
      (const __attribute__((address_space(1))) unsigned int*)g,
      (__attribute__((address_space(3))) unsigned int*)l, 16, 0, 0);
}

// ---------------- gating: logits = x @ wg, softmax, top-1 ----------------
__global__ __launch_bounds__(256) void moe_gating(const float* __restrict__ x,
                                                  const float* __restrict__ wg,
                                                  int* __restrict__ eidx,
                                                  float* __restrict__ gtok) {
  const int s = blockIdx.x * 4 + (threadIdx.x >> 6);
  const int lane = threadIdx.x & 63;
  const float* xr = x + (size_t)s * DDIM;
  float acc[NEXP];
#pragma unroll
  for (int e = 0; e < NEXP; ++e) acc[e] = 0.f;
  for (int d = lane; d < DDIM; d += 64) {
    float xv = xr[d];
    const float4* wrow = (const float4*)(wg + (size_t)d * NEXP);
    float4 w0 = wrow[0], w1v = wrow[1];
    acc[0] += xv * w0.x;  acc[1] += xv * w0.y;
    acc[2] += xv * w0.z;  acc[3] += xv * w0.w;
    acc[4] += xv * w1v.x; acc[5] += xv * w1v.y;
    acc[6] += xv * w1v.z; acc[7] += xv * w1v.w;
  }
#pragma unroll
  for (int off = 32; off > 0; off >>= 1) {
#pragma unroll
    for (int e = 0; e < NEXP; ++e) acc[e] += __shfl_down(acc[e], off);
  }
  if (lane == 0) {
    int best = 0; float bv = acc[0];
#pragma unroll
    for (int e = 1; e < NEXP; ++e) if (acc[e] > bv) { bv = acc[e]; best = e; }
    float sum = 0.f;
#pragma unroll
    for (int e = 0; e < NEXP; ++e) sum += expf(acc[e] - bv);
    eidx[s] = best;
    gtok[s] = 1.f / sum;   // exp(best - max) == 1
  }
}

// ---------------- hierarchical ordered slot assignment ----------------
__global__ __launch_bounds__(64) void scanA(const int* __restrict__ eidx,
                                            int* __restrict__ cnt) {
  const int blk = blockIdx.x;        // 128 blocks x 64 tokens
  const int lane = threadIdx.x;
  int e = eidx[blk * 64 + lane];
#pragma unroll
  for (int w = 0; w < NEXP; ++w) {
    unsigned long long m = __ballot(e == w);
    if (lane == 0) cnt[blk * NEXP + w] = __popcll(m);
  }
}

__global__ __launch_bounds__(512) void scanB(const int* __restrict__ cnt,
                                             int* __restrict__ off) {
  const int w = threadIdx.x >> 6;
  const int l = threadIdx.x & 63;
  int c0 = cnt[(2 * l) * NEXP + w];
  int c1 = cnt[(2 * l + 1) * NEXP + w];
  int s = c0 + c1;
  int run = s;
#pragma unroll
  for (int d = 1; d < 64; d <<= 1) {
    int up = __shfl_up(run, d);
    if (l >= d) run += up;
  }
  int excl = run - s;
  off[(2 * l) * NEXP + w] = excl;
  off[(2 * l + 1) * NEXP + w] = excl + c0;
}

__global__ __launch_bounds__(64) void scanC(const int* __restrict__ eidx,
                                            const float* __restrict__ gtok,
                                            const int* __restrict__ off,
                                            int* __restrict__ s2t,
                                            float* __restrict__ rgate) {
  const int blk = blockIdx.x;
  const int lane = threadIdx.x;
  const int tok = blk * 64 + lane;
  int e = eidx[tok];
  float g = gtok[tok];
  const unsigned long long below = (1ull << lane) - 1ull;
#pragma unroll
  for (int w = 0; w < NEXP; ++w) {
    unsigned long long m = __ballot(e == w);
    if (e == w) {
      int slot = off[blk * NEXP + w] + __popcll(m & below);
      if (slot < CAP) { s2t[w * CAP + slot] = tok; rgate[w * CAP + slot] = g; }
    }
  }
}

// ---------------- dispatch: gather kept tokens, fp32 -> fp16 ----------------
__global__ __launch_bounds__(128) void moe_dispatch(const float* __restrict__ x,
                                                    const int* __restrict__ s2t,
                                                    _Float16* __restrict__ disp) {
  const int row = blockIdx.x;
  const int t = threadIdx.x;
  const int token = s2t[row];
  half8 v;
  if (token >= 0) {
    const float4* xr = (const float4*)(x + (size_t)token * DDIM);
    float4 a = xr[2 * t], b = xr[2 * t + 1];
    v[0] = (_Float16)a.x; v[1] = (_Float16)a.y; v[2] = (_Float16)a.z; v[3] = (_Float16)a.w;
    v[4] = (_Float16)b.x; v[5] = (_Float16)b.y; v[6] = (_Float16)b.z; v[7] = (_Float16)b.w;
  } else {
#pragma unroll
    for (int i = 0; i < 8; ++i) v[i] = (_Float16)0.f;
  }
  *(half8*)(disp + (size_t)row * DDIM + t * 8) = v;
}

// ---------------- grouped GEMM "fused-B v3": 2-deep B pipeline, phase-aligned ----------------
// C = A[z] @ B[z], A fp16 [M][K] (gload_lds + XOR swizzle), B fp32 [K][N] native ->
// reg-stage (2 named sets, 2 tiles ahead), cvt fp16, ds_write into [n][64k] XOR tile.
// BM=BN=128, BK=64. 256 thr = 4 waves (2Mx2N), wave tile 64x64. LDS 64 KB, 2 blk/CU.
// NO K-rotation: all blocks phase-aligned -> concurrent blocks sharing an A-panel /
// B-slab hit L2 multicast (r13 lesson: dephasing -> 618 MB FETCH, +100 us).
// Counted-vmcnt barrier: s_waitcnt vmcnt(8) lgkmcnt(0); s_barrier — leaves the
// NEXT write-set's 8 B-loads in flight; this iter's 4 A gload_lds are drained.
// Unroll-by-2: reg-set & buffer indices compile-time (rule #20).
// B swizzle f(n)=((n>>2)^n)&7 (write & read conflict-free, enumerated r12).
// Tile order m-fastest (concurrent blocks share B slab; live B/XCD = 4 MB = L2).
template <int KDIM, int NDIM, bool FIRST, int GX, int GY>
__global__ __launch_bounds__(256, 2) void ffn_gemm_f(const _Float16* __restrict__ A_set,
                                                     const float* __restrict__ B_set,
                                                     _Float16* __restrict__ Hout,
                                                     float* __restrict__ Y,
                                                     const int* __restrict__ s2t,
                                                     const float* __restrict__ rgate) {
  __shared__ __align__(16) _Float16 As[2 * 8192];   // [buf][128 rows][64 k]
  __shared__ __align__(16) _Float16 Bs[2 * 8192];   // [buf][128 n][64 k] (XOR chunks)
  constexpr int NT = KDIM / 64;
  constexpr int TILES = GX * GY;
  const int wg = blockIdx.x;
  const int swz = (wg & 7) * TILES + (wg >> 3);   // bijective; xcd == expert
  const int z = swz / TILES;
  const int s2 = swz % TILES;
  const int xx = s2 / GY;          // n-tile (slow)
  const int yy = s2 % GY;          // m-tile (fast) -> concurrent blocks share B
  const int m0 = yy * 128, n0 = xx * 128;

  const int tid = threadIdx.x;
  const _Float16* Ae = A_set + (size_t)z * 1024 * KDIM;
  const float* Be = B_set + (size_t)z * (size_t)KDIM * NDIM;

  // A staging (global_load_lds, source-XOR-swizzled, linear LDS dest)
  const int sr = tid >> 3;      // row within 32-row group
  const int sc = tid & 7;       // 16B chunk
  auto STAGE_A = [&](int buf, int kt) {
#pragma unroll
    for (int j = 0; j < 4; ++j) {
      int r = j * 32 + sr;
      load_lds16(Ae + (size_t)(m0 + r) * KDIM + kt * 64 + ((sc ^ (r & 7)) << 3),
                 As + buf * 8192 + j * 2048 + tid * 8);
    }
  };

  // B reg-staging: thread t -> n-quad q = t&31 (n = 4q..4q+3), k-rows kb..kb+7
  const int bq = tid & 31;
  const int bkb = (tid >> 5) * 8;
  auto LOAD_B = [&](float4* br, int kt) {
#pragma unroll
    for (int i = 0; i < 8; ++i)
      br[i] = *(const float4*)(Be + (size_t)(kt * 64 + bkb + i) * NDIM + n0 + 4 * bq);
  };
  auto WRITE_B = [&](const float4* br, int buf) {
    _Float16* Bb = Bs + buf * 8192;
#pragma unroll
    for (int w = 0; w < 4; ++w) {
      int n = 4 * bq + w;
      half8 h;
#pragma unroll
      for (int i = 0; i < 8; ++i) h[i] = (_Float16)br[i][w];
      int c = (bkb >> 3) ^ (((n >> 2) ^ n) & 7);
      *(half8*)(Bb + n * 64 + c * 8) = h;
    }
  };

  const int lane = tid & 63, wid = tid >> 6;
  const int wr = (wid >> 1) * 64;   // wave A-row base
  const int wc = (wid & 1) * 64;    // wave B-n base
  const int r32 = lane & 31;
  const int khalf = lane >> 5;
  int offA[2][4], offB[2][4];
#pragma unroll
  for (int t2 = 0; t2 < 2; ++t2)
#pragma unroll
    for (int kf = 0; kf < 4; ++kf) {
      int ra = wr + t2 * 32 + r32, c = kf * 2 + khalf;
      offA[t2][kf] = ra * 64 + ((c ^ (ra & 7)) << 3);
      int nb = wc + t2 * 32 + r32;
      offB[t2][kf] = nb * 64 + ((c ^ (((nb >> 2) ^ nb) & 7)) << 3);
    }

  f32x16 acc[2][2];
#pragma unroll
  for (int m = 0; m < 2; ++m)
#pragma unroll
    for (int n = 0; n < 2; ++n)
#pragma unroll
      for (int j = 0; j < 16; ++j) acc[m][n][j] = 0.f;

  auto COMPUTE = [&](int buf) {
    const _Float16* Ab = As + buf * 8192;
    const _Float16* Bb = Bs + buf * 8192;
    __builtin_amdgcn_s_setprio(1);
#pragma unroll
    for (int kf = 0; kf < 4; ++kf) {
      half8 a0 = *(const half8*)(Ab + offA[0][kf]);
      half8 a1 = *(const half8*)(Ab + offA[1][kf]);
      half8 b0 = *(const half8*)(Bb + offB[0][kf]);
      half8 b1 = *(const half8*)(Bb + offB[1][kf]);
      acc[0][0] = __builtin_amdgcn_mfma_f32_32x32x16_f16(a0, b0, acc[0][0], 0, 0, 0);
      acc[0][1] = __builtin_amdgcn_mfma_f32_32x32x16_f16(a0, b1, acc[0][1], 0, 0, 0);
      acc[1][0] = __builtin_amdgcn_mfma_f32_32x32x16_f16(a1, b0, acc[1][0], 0, 0, 0);
      acc[1][1] = __builtin_amdgcn_mfma_f32_32x32x16_f16(a1, b1, acc[1][1], 0, 0, 0);
    }
    __builtin_amdgcn_s_setprio(0);
  };

  // Counted-vmcnt barrier: keep the newest 8 VMEM (next B set) in flight.
#define BARRIER8 do { \
    asm volatile("s_waitcnt vmcnt(8) lgkmcnt(0)" ::: "memory"); \
    __builtin_amdgcn_sched_barrier(0); \
    __builtin_amdgcn_s_barrier(); \
    __builtin_amdgcn_sched_barrier(0); } while (0)

  float4 bregA[8], bregB[8];
  // prologue: tile 0 fully staged; tile 1's B-loads in flight across the barrier
  LOAD_B(bregA, 0);
  STAGE_A(0, 0);
  WRITE_B(bregA, 0);                       // waits bregA only (A4 newer)
  LOAD_B(bregB, 1 & (NT - 1));
  BARRIER8;                                // drains A4; bregB stays flying

#pragma unroll 1
  for (int i = 0; i < NT; i += 2) {
    // ---- even iter: compute buf0(tile i); publish buf1(tile i+1) ----
    STAGE_A(1, (i + 1) & (NT - 1));
    LOAD_B(bregA, (i + 2) & (NT - 1));   // 2 tiles ahead (wrapped junk at tail, unused)
    COMPUTE(0);
    WRITE_B(bregB, 1);
    BARRIER8;
    // ---- odd iter: compute buf1(tile i+1); publish buf0(tile i+2) ----
    if (i + 2 < NT) STAGE_A(0, (i + 2) & (NT - 1));
    LOAD_B(bregB, (i + 3) & (NT - 1));
    COMPUTE(1);
    if (i + 2 < NT) WRITE_B(bregA, 0);
    BARRIER8;
  }
#undef BARRIER8

  // epilogue: C/D layout col=lane&31, row=(reg&3)+8*(reg>>2)+4*(lane>>5)
#pragma unroll
  for (int mt = 0; mt < 2; ++mt) {
#pragma unroll
    for (int nt = 0; nt < 2; ++nt) {
      const int gcol = n0 + wc + nt * 32 + r32;
#pragma unroll
      for (int reg = 0; reg < 16; ++reg) {
        const int rowf = (reg & 3) + 8 * (reg >> 2) + 4 * khalf;
        const int grow = m0 + wr + mt * 32 + rowf;
        if (FIRST) {
          Hout[((size_t)z * 1024 + grow) * (size_t)NDIM + gcol] =
              (_Float16)fmaxf(acc[mt][nt][reg], 0.f);
        } else {
          int token = s2t[z * CAP + grow];
          if (token >= 0) {
            float g = rgate[z * CAP + grow];
            Y[(size_t)token * DDIM + gcol] = acc[mt][nt][reg] * g;
          }
        }
      }
    }
  }
}

extern "C" void kernel_launch(void* const* d_in, const int* in_sizes, int n_in,
                              void* d_out, int out_size, void* d_ws, size_t ws_size,
                              hipStream_t stream) {
  const float* x  = (const float*)d_in[0];
  const float* wg = (const float*)d_in[1];
  const float* w1 = (const float*)d_in[2];
  const float* w2 = (const float*)d_in[3];
  float* y = (float*)d_out;

  char* ws = (char*)d_ws;
  int*   eidx  = (int*)(ws);                 // 32 KB
  float* gtok  = (float*)(ws + 32768);       // 32 KB
  int*   s2t   = (int*)(ws + 65536);         // 32 KB
  float* rgate = (float*)(ws + 98304);       // 32 KB
  int*   cnt   = (int*)(ws + 131072);        // 4 KB
  int*   off   = (int*)(ws + 135168);        // 4 KB
  _Float16* disp = (_Float16*)(ws + 147456); // 16 MB
  _Float16* hbuf = (_Float16*)(ws + 147456 + (size_t)NEXP * CAP * DDIM * 2);  // 64 MB

  moe_gating<<<S_TOK / 4, 256, 0, stream>>>(x, wg, eidx, gtok);
  scanA<<<128, 64, 0, stream>>>(eidx, cnt);
  scanB<<<1, 512, 0, stream>>>(cnt, off);
  (void)hipMemsetAsync(s2t, 0xFF, 32768, stream);
  (void)hipMemsetAsync(rgate, 0, 32768, stream);
  scanC<<<128, 64, 0, stream>>>(eidx, gtok, off, s2t, rgate);
  moe_dispatch<<<NEXP * CAP, 128, 0, stream>>>(x, s2t, disp);
  (void)hipMemsetAsync(d_out, 0, (size_t)out_size * sizeof(float), stream);

  // GEMM1: disp[C,1024] x w1[1024,4096] -> relu -> hbuf. 8e x (32n x 8m) = 2048 blocks
  ffn_gemm_f<DDIM, HDIM, true, 32, 8><<<2048, 256, 0, stream>>>(
      disp, w1, hbuf, nullptr, nullptr, nullptr);

  // GEMM2: hbuf[C,4096] x w2[4096,1024] -> scatter to y. 8e x (8n x 8m) = 512 blocks
  ffn_gemm_f<HDIM, DDIM, false, 8, 8><<<512, 256, 0, stream>>>(
      hbuf, w2, nullptr, y, s2t, rgate);
}